// Round 5
// baseline (170.307 us; speedup 1.0000x reference)
//
#include <hip/hip_runtime.h>
#include <math.h>

// TopKSoftMax: rows of D=64 f32; keep top-8 (ties -> lower index, exactly as
// jax.lax.top_k), softmax over kept, zeros elsewhere.
//
// R5: persistent 1-wave blocks + double-buffered LDS + counted vmcnt pipeline.
// R4's per-block life was [load burst -> vmcnt(0) -> compute -> store-drain ->
// endpgm -> relaunch]: ~30% of each wave slot's time had no reads in flight.
// Here 1280 blocks (5/CU, 32KB LDS each) loop over ~13 contiguous 64-row tiles,
// prefetching tile t+1 into the other buffer while computing tile t. Waits are
// counted, never vmcnt(0) in steady state: at the wait for L(t), newer vmem ops
// are exactly S(t-1)=16 stores + L(t+1)=16 loads -> vmcnt(32) (vmcnt retires
// in issue order). Transpose logic identical to R4 (verified):
//   LDS slot(r,k) = r*16 + (k ^ (r&15)); all 4 access patterns bank-uniform.

#define D4 16
#define THREADS 64
#define TILE_F4 1024               // 64 rows x 16 float4
#define MAX_BLOCKS 1280            // 256 CUs x 5 resident (32 KB LDS each)

// one level of the sorted-insert chain: ti = max(ti, a); a = min(ti_old, a)
#define LVL(ti) { const float _hi = fmaxf(ti, _a); _a = fminf(ti, _a); ti = _hi; }
#define INSERT(x) { float _a = (x); \
    LVL(t0) LVL(t1) LVL(t2) LVL(t3) LVL(t4) LVL(t5) LVL(t6) \
    t7 = fmaxf(t7, _a); }

// keep if strictly > thr, or == thr while index-ordered quota remains
#define PROC(x, o) { \
    const int _kgt = ((x) > thr); \
    const int _keq = ((x) == thr) & (quota > 0); \
    quota -= _keq; \
    (o) = (_kgt | _keq) ? __expf((x) - m) * inv : 0.0f; }

#define WAITV(N) asm volatile("s_waitcnt vmcnt(" #N ")" ::: "memory")

__device__ __forceinline__ void gload_lds16(const void* g, void* l) {
    __builtin_amdgcn_global_load_lds(
        (__attribute__((address_space(1))) void*)(g),
        (__attribute__((address_space(3))) void*)(l),
        16, 0, 0);   // 16B/lane -> global_load_lds_dwordx4
}

// 16x global_load_lds_dwordx4; source pre-swizzled so linear LDS dest becomes
// the XOR-swizzled tile: slot r*16 + (k^(r&15)) <- (row r, float4 k)
__device__ __forceinline__ void issue_tile(const float4* __restrict__ p,
                                           float4* t, int lane) {
    #pragma unroll
    for (int c = 0; c < D4; ++c) {
        const int r = c * 4 + (lane >> 4);
        const int k = (lane & 15) ^ (r & 15);
        gload_lds16(p + r * 16 + k, t + c * 64);
    }
}

__device__ __forceinline__ void topk_softmax_row(float4 (&v)[D4]) {
    float t0 = -INFINITY, t1 = -INFINITY, t2 = -INFINITY, t3 = -INFINITY,
          t4 = -INFINITY, t5 = -INFINITY, t6 = -INFINITY, t7 = -INFINITY;
    #pragma unroll
    for (int c = 0; c < D4; ++c) {
        INSERT(v[c].x) INSERT(v[c].y) INSERT(v[c].z) INSERT(v[c].w)
    }
    const float thr = t7;            // 8th order statistic
    const float m   = t0;            // row max
    int quota = 8 - ((t0 > thr) + (t1 > thr) + (t2 > thr) + (t3 > thr) +
                     (t4 > thr) + (t5 > thr) + (t6 > thr));
    const float sum = __expf(t0 - m) + __expf(t1 - m) + __expf(t2 - m) + __expf(t3 - m) +
                      __expf(t4 - m) + __expf(t5 - m) + __expf(t6 - m) + __expf(t7 - m);
    const float inv = 1.0f / sum;
    #pragma unroll
    for (int c = 0; c < D4; ++c) {
        float4 o;
        PROC(v[c].x, o.x) PROC(v[c].y, o.y) PROC(v[c].z, o.z) PROC(v[c].w, o.w)
        v[c] = o;
    }
}

// caller must have waited for this buffer's loads (counted vmcnt)
__device__ __forceinline__ void process_tile(float4* t, float4* __restrict__ q,
                                             int lane) {
    const int swz = lane & 15;
    float4 v[D4];
    #pragma unroll
    for (int c = 0; c < D4; ++c) v[c] = t[lane * 16 + (c ^ swz)];   // own row

    topk_softmax_row(v);

    #pragma unroll
    for (int c = 0; c < D4; ++c) t[lane * 16 + (c ^ swz)] = v[c];   // writeback
    asm volatile("s_waitcnt lgkmcnt(0)" ::: "memory");              // cross-lane

    #pragma unroll
    for (int c = 0; c < D4; ++c) {                                  // coalesced out
        const int r = c * 4 + (lane >> 4);
        q[c * 64 + lane] = t[r * 16 + ((lane & 15) ^ (r & 15))];
    }
}

__global__ __launch_bounds__(THREADS)
void topk_softmax_pipe(const float* __restrict__ in,
                       float* __restrict__ out,
                       int ntiles, int nblocks)
{
    __shared__ float4 ldsA[TILE_F4];   // 16 KB
    __shared__ float4 ldsB[TILE_F4];   // 16 KB

    const int lane = threadIdx.x;      // 64-thread block == one wave
    const int b = blockIdx.x;
    const int qt = ntiles / nblocks, rt = ntiles % nblocks;
    const int ta = b * qt + (b < rt ? b : rt);
    const int tb = ta + qt + (b < rt ? 1 : 0);
    if (ta >= tb) return;

    const float4* __restrict__ in4 = reinterpret_cast<const float4*>(in);
    float4* __restrict__ out4      = reinterpret_cast<float4*>(out);

    int t = ta;
    issue_tile(in4 + (long long)t * TILE_F4, ldsA, lane);
    if (t + 1 < tb) {
        issue_tile(in4 + (long long)(t + 1) * TILE_F4, ldsB, lane);
        WAITV(16);                 // L(t) done; L(t+1) stays in flight
    } else {
        WAITV(0);
    }

    for (;;) {
        // ---- tile t in A; B holds/receives t+1 ----
        process_tile(ldsA, out4 + (long long)t * TILE_F4, lane);
        if (t + 2 < tb) {
            __builtin_amdgcn_sched_barrier(0);   // don't hoist above A's out-reads
            issue_tile(in4 + (long long)(t + 2) * TILE_F4, ldsA, lane);
        }
        ++t; if (t >= tb) break;
        // need L(t) done; newer = S(t-1)=16 [+ L(t+1)=16 if issued]
        if (t + 1 < tb) WAITV(32); else WAITV(16);

        // ---- tile t in B; A holds/receives t+1 ----
        process_tile(ldsB, out4 + (long long)t * TILE_F4, lane);
        if (t + 2 < tb) {
            __builtin_amdgcn_sched_barrier(0);
            issue_tile(in4 + (long long)(t + 2) * TILE_F4, ldsB, lane);
        }
        ++t; if (t >= tb) break;
        if (t + 1 < tb) WAITV(32); else WAITV(16);
    }
}

// remainder rows (nrows % 64) — not taken at this problem size
__global__ __launch_bounds__(THREADS)
void topk_softmax_tail(const float* __restrict__ in, float* __restrict__ out,
                       long long row0, long long nrows)
{
    const long long row = row0 + threadIdx.x;
    if (row >= nrows) return;
    const float4* __restrict__ p = reinterpret_cast<const float4*>(in) + row * D4;
    float4* __restrict__ q       = reinterpret_cast<float4*>(out)      + row * D4;
    float4 v[D4];
    #pragma unroll
    for (int c = 0; c < D4; ++c) v[c] = p[c];
    topk_softmax_row(v);
    #pragma unroll
    for (int c = 0; c < D4; ++c) q[c] = v[c];
}

extern "C" void kernel_launch(void* const* d_in, const int* in_sizes, int n_in,
                              void* d_out, int out_size, void* d_ws, size_t ws_size,
                              hipStream_t stream) {
    const float* in = (const float*)d_in[0];
    float* out = (float*)d_out;
    const long long nrows = in_sizes[0] / 64;
    const int ntiles = (int)(nrows / 64);
    const long long rem = nrows - (long long)ntiles * 64;

    if (ntiles > 0) {
        const int nblocks = ntiles < MAX_BLOCKS ? ntiles : MAX_BLOCKS;
        topk_softmax_pipe<<<nblocks, THREADS, 0, stream>>>(in, out, ntiles, nblocks);
    }
    if (rem > 0) {
        topk_softmax_tail<<<1, THREADS, 0, stream>>>(in, out, (long long)ntiles * 64, nrows);
    }
}